// Round 6
// baseline (1088.480 us; speedup 1.0000x reference)
//
#include <hip/hip_runtime.h>

#define EE      640000
#define NNODES_ 10000
#define NG      64
#define DN      128
#define DE      32
#define HID     128
#define DOUT    64
#define NMT     (EE / 16)
#define SLOWNB  768
#define FNB     128

// ---- workspace float-element offsets ----
#define ACCF  0        // [64][128] per-graph sum of a (slow path only)
#define CNTF  8192     // [64] edge count per graph (fp32)
#define S1F   8256     // [128] global sum(a)   (slow path only)
#define S2F   8384     // [128] global sum(a^2) (slow path only)
#define GXF   8512     // [64][128] per-graph node sums
#define O1F   16704    // [64][128] mlp2 hidden
#define FLGF  24896    // int flags
#define BAT8  24898    // 10240 u8
#define W1F_  27458    // 160*128 fp32
#define B1F_  47938
#define G1F_  48066
#define BE1F_ 48194
#define W2F_  48322
#define B2F_  64706
#define W3F_  64834
#define B3F_  97602
#define G3F_  97730
#define BE3F_ 97858
#define W4F_  97986
#define B4F_  106178
#define YBF   106244   // bf16 y[10000][128]; byte 424,976
#define PARTF 746244   // partial copies: ncopy x 8448 floats
#define PSZ   8448     // 8192 acc + 256 stats

typedef __bf16 bf16x8 __attribute__((ext_vector_type(8)));
typedef float  f32x4  __attribute__((ext_vector_type(4)));

__device__ __forceinline__ float lrelu(float v) { return v > 0.f ? v : 0.01f * v; }

__device__ __forceinline__ bf16x8 cvt8(const float* p) {
  const f32x4 a0 = *(const f32x4*)p, a1 = *(const f32x4*)(p + 4);
  bf16x8 t;
  t[0]=(__bf16)a0[0]; t[1]=(__bf16)a0[1]; t[2]=(__bf16)a0[2]; t[3]=(__bf16)a0[3];
  t[4]=(__bf16)a1[0]; t[5]=(__bf16)a1[1]; t[6]=(__bf16)a1[2]; t[7]=(__bf16)a1[3];
  return t;
}

// ---- K0: dtype sniff + zero accumulator head ----
__global__ __launch_bounds__(256) void k_sniff(const unsigned* __restrict__ xw,
                                               const unsigned* __restrict__ ew,
                                               float* __restrict__ ws) {
  const int tid = threadIdx.x;
  for (int i = tid; i < 8512; i += 256) ws[i] = 0.f;
  if (tid < 64) {
    const unsigned w = xw[tid];
    const unsigned ex = (w >> 7) & 0xFFu;
    int cb = (ex >= 100u && ex <= 140u) ? 1 : 0;
    int ci = (ew[2 * tid + 1] == 0u) ? 1 : 0;
#pragma unroll
    for (int s = 1; s < 64; s <<= 1) { cb += __shfl_xor(cb, s); ci += __shfl_xor(ci, s); }
    if (tid == 0) { int* f = (int*)(ws + FLGF); f[0] = (cb >= 48); f[1] = (ci >= 60); }
  }
}

__device__ __forceinline__ void cpyw(float* dst, const void* src, int n, int isb,
                                     int gtid, int gs) {
  if (isb) { const __bf16* s = (const __bf16*)src;
    for (int i = gtid; i < n; i += gs) dst[i] = (float)s[i];
  } else { const float* s = (const float*)src;
    for (int i = gtid; i < n; i += gs) dst[i] = s[i]; }
}

// ---- K1: weights->fp32, bat8 table, edge-count hist, zero partials (atomic tier) ----
__global__ __launch_bounds__(256) void k_norm(
    const void* __restrict__ eidx, const void* __restrict__ batch,
    const void* W1, const void* b1, const void* g1, const void* be1,
    const void* W2, const void* b2, const void* W3, const void* b3,
    const void* g3, const void* be3, const void* W4, const void* b4,
    float* __restrict__ ws, const int ncopy) {
  const int gtid = blockIdx.x * 256 + threadIdx.x;
  const int gs = gridDim.x * 256;
  const int* f = (const int*)(ws + FLGF);
  const int isb = f[0], isi = f[1];
  cpyw(ws + W1F_, W1, 160 * HID, isb, gtid, gs);
  cpyw(ws + B1F_, b1, HID, isb, gtid, gs);
  cpyw(ws + G1F_, g1, HID, isb, gtid, gs);
  cpyw(ws + BE1F_, be1, HID, isb, gtid, gs);
  cpyw(ws + W2F_, W2, HID * HID, isb, gtid, gs);
  cpyw(ws + B2F_, b2, HID, isb, gtid, gs);
  cpyw(ws + W3F_, W3, 256 * HID, isb, gtid, gs);
  cpyw(ws + B3F_, b3, HID, isb, gtid, gs);
  cpyw(ws + G3F_, g3, HID, isb, gtid, gs);
  cpyw(ws + BE3F_, be3, HID, isb, gtid, gs);
  cpyw(ws + W4F_, W4, HID * DOUT, isb, gtid, gs);
  cpyw(ws + B4F_, b4, DOUT, isb, gtid, gs);
  if (ncopy > 0 && ncopy < FNB)   // atomic tier needs zero-init; private tier overwrites
    for (int i = gtid; i < ncopy * PSZ; i += gs) ws[PARTF + i] = 0.f;
  const int* bs = (const int*)batch;
  unsigned char* b8 = (unsigned char*)(ws + BAT8);
  for (int i = gtid; i < NNODES_; i += gs)
    b8[i] = (unsigned char)((isi ? bs[2 * i] : bs[i]) & 63);
  __shared__ int h[NG];
  if (threadIdx.x < NG) h[threadIdx.x] = 0;
  __syncthreads();
  const int* es = (const int*)eidx;
  for (int e = gtid; e < EE; e += gs) {
    int cl = isi ? es[2 * (EE + e)] : es[EE + e];
    cl = min(max(cl, 0), NNODES_ - 1);
    const int g = (isi ? bs[2 * cl] : bs[cl]) & 63;
    atomicAdd(&h[g], 1);
  }
  __syncthreads();
  if (threadIdx.x < NG && h[threadIdx.x])
    unsafeAtomicAdd(&ws[CNTF + threadIdx.x], (float)h[threadIdx.x]);
}

// ---- K2: per-graph node-feature sums (batch sorted) ----
__global__ __launch_bounds__(256) void k_gx(
    const void* __restrict__ x, const void* __restrict__ batch, float* __restrict__ ws) {
  const int b = blockIdx.x, tid = threadIdx.x;
  const int isb = ((const int*)(ws + FLGF))[0];
  const int isi = ((const int*)(ws + FLGF))[1];
  const int* bt = (const int*)batch;
#define BATV(i) ((isi ? bt[2 * (i)] : bt[(i)]) & 63)
  int lo = 0, hi = NNODES_;
  while (lo < hi) { int m = (lo + hi) >> 1; if (BATV(m) < b) lo = m + 1; else hi = m; }
  const int r0 = lo;
  hi = NNODES_;
  while (lo < hi) { int m = (lo + hi) >> 1; if (BATV(m) < b + 1) lo = m + 1; else hi = m; }
  const int r1 = lo;
#undef BATV
  const int c = tid & 127, half = tid >> 7;
  float acc = 0.f;
  if (isb) { const __bf16* xs = (const __bf16*)x;
    for (int r = r0 + half; r < r1; r += 2) acc += (float)xs[r * DN + c];
  } else { const float* xs = (const float*)x;
    for (int r = r0 + half; r < r1; r += 2) acc += xs[r * DN + c]; }
  __shared__ float red[256];
  red[tid] = acc;
  __syncthreads();
  if (tid < 128) ws[GXF + b * DN + tid] = red[tid] + red[tid + 128];
}

// ---- K3a: y = x @ W1x + b1 (bf16 out) ----
__global__ __launch_bounds__(256) void k_y(float* __restrict__ ws, const void* __restrict__ x) {
  __shared__ __align__(16) __bf16 w1x[128 * 128];
  const int tid = threadIdx.x;
  const int isb = ((const int*)(ws + FLGF))[0];
  for (int i = tid; i < 128 * 128; i += 256) {
    const int k = i >> 7, n = i & 127;
    w1x[n * 128 + k] = (__bf16)ws[W1F_ + k * HID + n];
  }
  __syncthreads();
  const int lane = tid & 63, wid = tid >> 6, ml = lane & 15, kg = lane >> 4;
  __bf16* ybf = (__bf16*)(ws + YBF);
  for (int t = blockIdx.x * 4 + wid; t < 625; t += 160 * 4) {
    const int n0 = t * 16;
    const int row = n0 + ml;
    bf16x8 af[4];
    if (isb) {
      const __bf16* xp = (const __bf16*)x + row * DN + kg * 8;
#pragma unroll
      for (int ks = 0; ks < 4; ++ks) af[ks] = *(const bf16x8*)(xp + ks * 32);
    } else {
      const float* xp = (const float*)x + row * DN + kg * 8;
#pragma unroll
      for (int ks = 0; ks < 4; ++ks) af[ks] = cvt8(xp + ks * 32);
    }
    f32x4 acc[8] = {{0,0,0,0},{0,0,0,0},{0,0,0,0},{0,0,0,0},
                    {0,0,0,0},{0,0,0,0},{0,0,0,0},{0,0,0,0}};
#pragma unroll
    for (int ks = 0; ks < 4; ++ks) {
#pragma unroll
      for (int nt = 0; nt < 8; ++nt) {
        const bf16x8 bfr = *(const bf16x8*)(w1x + (nt * 16 + ml) * 128 + ks * 32 + kg * 8);
        acc[nt] = __builtin_amdgcn_mfma_f32_16x16x32_bf16(af[ks], bfr, acc[nt], 0, 0, 0);
      }
    }
#pragma unroll
    for (int nt = 0; nt < 8; ++nt) {
      const int c = nt * 16 + ml;
      const float bias = ws[B1F_ + c];
#pragma unroll
      for (int q = 0; q < 4; ++q)
        ybf[(n0 + kg * 4 + q) * HID + c] = (__bf16)(acc[nt][q] + bias);
    }
  }
}

// ---- K3b: edge loop; flush to per-block private partial (plain stores) ----
__global__ __launch_bounds__(512) void k_edgef(float* __restrict__ ws,
                                               const void* __restrict__ ea,
                                               const void* __restrict__ eidx,
                                               const int ncopy) {
  __shared__ __align__(16) float smem[NG * 132];
  __shared__ float sstat[256];
  const int tid = threadIdx.x;
  const int* flg = (const int*)(ws + FLGF);
  const int isb = flg[0], isi = flg[1];
  __bf16* w1e = (__bf16*)smem;                      // staging overlay
  for (int i = tid; i < 32 * 128; i += 512) {
    const int k = i >> 7, n = i & 127;
    w1e[n * 32 + k] = (__bf16)ws[W1F_ + (128 + k) * HID + n];
  }
  __syncthreads();
  const int lane = tid & 63, wid = tid >> 6, ml = lane & 15, kg = lane >> 4;
  bf16x8 bfe[8];
#pragma unroll
  for (int nt = 0; nt < 8; ++nt)
    bfe[nt] = *(const bf16x8*)(w1e + (nt * 16 + ml) * 32 + kg * 8);
  bf16x8 idf;
#pragma unroll
  for (int j = 0; j < 8; ++j) idf[j] = (kg * 8 + j == ml) ? (__bf16)1.0f : (__bf16)0.0f;
  __syncthreads();
  for (int i = tid; i < NG * 132; i += 512) smem[i] = 0.f;
  for (int i = tid; i < 256; i += 512) sstat[i] = 0.f;
  __syncthreads();

  const int* ei32 = (const int*)eidx;
  const unsigned char* bat8 = (const unsigned char*)(ws + BAT8);
  const __bf16* ybf = (const __bf16*)(ws + YBF);
  float s1[8] = {0,0,0,0,0,0,0,0}, s2[8] = {0,0,0,0,0,0,0,0};

  const int TSTR = FNB * 8;
  int t = blockIdx.x * 8 + wid;
  int pr_r = 0, pr_g = 0;
  bf16x8 pr_ae;
  if (t < NMT) {
    const int em = t * 16 + ml;
    int r_ = isi ? ei32[2 * em] : ei32[em];
    int c_ = isi ? ei32[2 * (EE + em)] : ei32[EE + em];
    pr_r = min(max(r_, 0), NNODES_ - 1);
    pr_g = bat8[min(max(c_, 0), NNODES_ - 1)];
    pr_ae = isb ? *(const bf16x8*)((const __bf16*)ea + em * DE + kg * 8)
                : cvt8((const float*)ea + em * DE + kg * 8);
  }
  while (t < NMT) {
    const int r = pr_r, gg = pr_g;
    const bf16x8 ae = pr_ae;
    const int tn = t + TSTR;
    if (tn < NMT) {   // prefetch next tile's indices + ea
      const int em = tn * 16 + ml;
      int r_ = isi ? ei32[2 * em] : ei32[em];
      int c_ = isi ? ei32[2 * (EE + em)] : ei32[EE + em];
      pr_r = min(max(r_, 0), NNODES_ - 1);
      pr_g = bat8[min(max(c_, 0), NNODES_ - 1)];
      pr_ae = isb ? *(const bf16x8*)((const __bf16*)ea + em * DE + kg * 8)
                  : cvt8((const float*)ea + em * DE + kg * 8);
    }
    f32x4 acc[8] = {{0,0,0,0},{0,0,0,0},{0,0,0,0},{0,0,0,0},
                    {0,0,0,0},{0,0,0,0},{0,0,0,0},{0,0,0,0}};
    const __bf16* yb = ybf + r * HID + (kg & 1) * 8;
#pragma unroll
    for (int nt = 0; nt < 8; ++nt) {
      const bf16x8 ay = *(const bf16x8*)(yb + nt * 16);
      acc[nt] = __builtin_amdgcn_mfma_f32_16x16x32_bf16(ae, bfe[nt], acc[nt], 0, 0, 0);
      acc[nt] = __builtin_amdgcn_mfma_f32_16x16x32_bf16(ay, idf, acc[nt], 0, 0, 0);
    }
    int gR[4];
#pragma unroll
    for (int q = 0; q < 4; ++q) gR[q] = __shfl(gg, kg * 4 + q);
#pragma unroll
    for (int nt = 0; nt < 8; ++nt) {
      const int c = nt * 16 + ml;
#pragma unroll
      for (int q = 0; q < 4; ++q) {
        const float v = lrelu(acc[nt][q]);
        s1[nt] += v;
        s2[nt] += v * v;
        atomicAdd(&smem[gR[q] * 132 + c], v);   // ds_add_f32
      }
    }
    t = tn;
  }
#pragma unroll
  for (int nt = 0; nt < 8; ++nt) {
    float v1 = s1[nt], v2 = s2[nt];
    v1 += __shfl_xor(v1, 16); v1 += __shfl_xor(v1, 32);
    v2 += __shfl_xor(v2, 16); v2 += __shfl_xor(v2, 32);
    if (kg == 0) {
      atomicAdd(&sstat[nt * 16 + ml], v1);
      atomicAdd(&sstat[128 + nt * 16 + ml], v2);
    }
  }
  __syncthreads();
  float* part = ws + PARTF + (size_t)(blockIdx.x & (ncopy - 1)) * PSZ;
  if (ncopy == FNB) {   // private copy: plain stores, zero atomics
    for (int i = tid; i < NG * HID; i += 512)
      part[i] = smem[(i >> 7) * 132 + (i & 127)];
    if (tid < 256) part[8192 + tid] = sstat[tid];
  } else {              // shared copies: low-contention atomics
    for (int i = tid; i < NG * HID; i += 512)
      unsafeAtomicAdd(&part[i], smem[(i >> 7) * 132 + (i & 127)]);
    if (tid < 256) unsafeAtomicAdd(&part[8192 + tid], sstat[tid]);
  }
}

// ---- K3s: slow fallback (proven) ----
__global__ __launch_bounds__(256) void k_edges_slow(
    float* __restrict__ ws, const void* __restrict__ x, const void* __restrict__ ea,
    const void* __restrict__ eidx) {
  __shared__ __align__(16) char smem[40960];
  float* lacc = (float*)smem;
  __bf16* w1t = (__bf16*)smem;
  const int tid = threadIdx.x;
  const int* flg = (const int*)(ws + FLGF);
  const int isb = flg[0], isi = flg[1];
  for (int i = tid; i < 160 * HID; i += 256) {
    const int k = i >> 7, n = i & 127;
    w1t[n * 160 + k] = (__bf16)ws[W1F_ + i];
  }
  __syncthreads();
  const int lane = tid & 63, wid = tid >> 6;
  const int ml = lane & 15, kg = lane >> 4;
  const int ch0 = (wid & 1) * 64;
  const int pair = blockIdx.x * 2 + (wid >> 1);
  bf16x8 bfr[5][4];
  float b1v[4];
#pragma unroll
  for (int nt = 0; nt < 4; ++nt) {
    const int n = ch0 + nt * 16 + ml;
    b1v[nt] = ws[B1F_ + n];
#pragma unroll
    for (int ks = 0; ks < 5; ++ks)
      bfr[ks][nt] = *(const bf16x8*)(w1t + n * 160 + ks * 32 + kg * 8);
  }
  __syncthreads();
  for (int i = tid; i < NG * 132; i += 256) lacc[i] = 0.f;
  __syncthreads();
  float s1a[4] = {0,0,0,0}, s2a[4] = {0,0,0,0};
  const int* ei32 = (const int*)eidx;
  const unsigned char* bat8 = (const unsigned char*)(ws + BAT8);
  for (int mt = pair; mt < NMT; mt += 2 * SLOWNB) {
    const int em = mt * 16 + ml;
    int r  = isi ? ei32[2 * em] : ei32[em];
    int cl = isi ? ei32[2 * (EE + em)] : ei32[EE + em];
    r  = min(max(r, 0), NNODES_ - 1);
    cl = min(max(cl, 0), NNODES_ - 1);
    const int gg = bat8[cl];
    f32x4 acc[4] = {{0,0,0,0},{0,0,0,0},{0,0,0,0},{0,0,0,0}};
#pragma unroll
    for (int ks = 0; ks < 4; ++ks) {
      bf16x8 afr;
      if (isb) afr = *(const bf16x8*)((const __bf16*)x + r * DN + ks * 32 + kg * 8);
      else     afr = cvt8((const float*)x + r * DN + ks * 32 + kg * 8);
#pragma unroll
      for (int nt = 0; nt < 4; ++nt)
        acc[nt] = __builtin_amdgcn_mfma_f32_16x16x32_bf16(afr, bfr[ks][nt], acc[nt], 0, 0, 0);
    }
    {
      bf16x8 t;
      if (isb) t = *(const bf16x8*)((const __bf16*)ea + em * DE + kg * 8);
      else     t = cvt8((const float*)ea + em * DE + kg * 8);
#pragma unroll
      for (int nt = 0; nt < 4; ++nt)
        acc[nt] = __builtin_amdgcn_mfma_f32_16x16x32_bf16(t, bfr[4][nt], acc[nt], 0, 0, 0);
    }
    int gR[4];
#pragma unroll
    for (int q = 0; q < 4; ++q) gR[q] = __shfl(gg, kg * 4 + q);
#pragma unroll
    for (int nt = 0; nt < 4; ++nt) {
      const int c = ch0 + nt * 16 + ml;
#pragma unroll
      for (int q = 0; q < 4; ++q) {
        const float v = lrelu(acc[nt][q] + b1v[nt]);
        s1a[nt] += v;
        s2a[nt] += v * v;
        atomicAdd(&lacc[gR[q] * 132 + c], v);
      }
    }
  }
#pragma unroll
  for (int nt = 0; nt < 4; ++nt) {
    float v1 = s1a[nt], v2 = s2a[nt];
    v1 += __shfl_xor(v1, 16); v1 += __shfl_xor(v1, 32);
    v2 += __shfl_xor(v2, 16); v2 += __shfl_xor(v2, 32);
    if (lane < 16) {
      unsafeAtomicAdd(&ws[S1F + ch0 + nt * 16 + lane], v1);
      unsafeAtomicAdd(&ws[S2F + ch0 + nt * 16 + lane], v2);
    }
  }
  __syncthreads();
  for (int i = tid; i < NG * HID; i += 256)
    unsafeAtomicAdd(&ws[ACCF + i], lacc[(i >> 7) * 132 + (i & 127)]);
}

// ---- K4: reduce partials + BN1-affine + go GEMM + MLP2 layer1 ----
__global__ __launch_bounds__(128) void k_graph(float* __restrict__ ws, const int ncopy) {
  const int b = blockIdx.x, c = threadIdx.x;
  float sa = ws[ACCF + b * HID + c];
  float s1 = ws[S1F + c], s2 = ws[S2F + c];
  for (int p = 0; p < ncopy; ++p) {
    const float* part = ws + PARTF + (size_t)p * PSZ;
    sa += part[b * HID + c];
    s1 += part[8192 + c];
    s2 += part[8192 + 128 + c];
  }
  const float invE = 1.f / (float)EE;
  const float mu  = s1 * invE;
  const float var = s2 * invE - mu * mu;
  const float s   = ws[G1F_ + c] * rsqrtf(var + 1e-5f);
  const float t   = ws[BE1F_ + c] - mu * s;
  const float cb  = ws[CNTF + b];
  __shared__ float zsh[HID];
  __shared__ float gv[DN + HID];
  zsh[c] = s * sa + cb * t;
  gv[c]  = ws[GXF + b * DN + c];
  __syncthreads();
  float a = cb * ws[B2F_ + c];
  for (int k = 0; k < HID; ++k) a += zsh[k] * ws[W2F_ + k * HID + c];
  gv[DN + c] = a;
  __syncthreads();
  float h = ws[B3F_ + c];
  for (int j = 0; j < DN + HID; ++j) h += gv[j] * ws[W3F_ + j * HID + c];
  ws[O1F + b * HID + c] = lrelu(h);
}

// ---- K5: BN over graphs + final Lin(128,64) ----
__global__ __launch_bounds__(64) void k_out(const float* __restrict__ ws,
                                            void* __restrict__ out) {
  const int b = blockIdx.x, o = threadIdx.x;
  const int isb = ((const int*)(ws + FLGF))[0];
  __shared__ float zrow[HID];
  for (int cc = o; cc < HID; cc += 64) {
    float sm = 0.f, sq = 0.f;
    for (int r = 0; r < NG; ++r) { const float v = ws[O1F + r * HID + cc]; sm += v; sq += v * v; }
    const float mu  = sm * (1.f / NG);
    const float var = sq * (1.f / NG) - mu * mu;
    const float sc  = ws[G3F_ + cc] * rsqrtf(var + 1e-5f);
    zrow[cc] = ws[O1F + b * HID + cc] * sc + (ws[BE3F_ + cc] - mu * sc);
  }
  __syncthreads();
  float a = ws[B4F_ + o];
  for (int k = 0; k < HID; ++k) a += zrow[k] * ws[W4F_ + k * DOUT + o];
  if (isb) ((__bf16*)out)[b * DOUT + o] = (__bf16)a;
  else     ((float*)out)[b * DOUT + o] = a;
}

extern "C" void kernel_launch(void* const* d_in, const int* in_sizes, int n_in,
                              void* d_out, int out_size, void* d_ws, size_t ws_size,
                              hipStream_t stream) {
  float* ws = (float*)d_ws;
  const size_t need128 = (size_t)(PARTF + 128 * PSZ) * 4;  // 7,310,352 B
  const size_t need32  = (size_t)(PARTF + 32 * PSZ) * 4;   // 4,066,320 B
  const int ncopy = (ws_size >= need128) ? 128 : ((ws_size >= need32) ? 32 : 0);
  hipLaunchKernelGGL(k_sniff, dim3(1), dim3(256), 0, stream,
                     (const unsigned*)d_in[0], (const unsigned*)d_in[1], ws);
  hipLaunchKernelGGL(k_norm, dim3(256), dim3(256), 0, stream,
                     d_in[1], d_in[4],
                     d_in[5], d_in[6], d_in[7], d_in[8],
                     d_in[9], d_in[10], d_in[11], d_in[12],
                     d_in[13], d_in[14], d_in[15], d_in[16], ws, ncopy);
  hipLaunchKernelGGL(k_gx, dim3(NG), dim3(256), 0, stream, d_in[0], d_in[4], ws);
  if (ncopy > 0) {
    hipLaunchKernelGGL(k_y, dim3(160), dim3(256), 0, stream, ws, d_in[0]);
    hipLaunchKernelGGL(k_edgef, dim3(FNB), dim3(512), 0, stream, ws, d_in[2], d_in[1], ncopy);
  } else {
    hipLaunchKernelGGL(k_edges_slow, dim3(SLOWNB), dim3(256), 0, stream,
                       ws, d_in[0], d_in[2], d_in[1]);
  }
  hipLaunchKernelGGL(k_graph, dim3(NG), dim3(128), 0, stream, ws, ncopy);
  hipLaunchKernelGGL(k_out, dim3(NG), dim3(64), 0, stream, ws, d_out);
}

// Round 9
// 392.045 us; speedup vs baseline: 2.7764x; 2.7764x over previous
//
#include <hip/hip_runtime.h>

#define EE      640000
#define NNODES_ 10000
#define NG      64
#define DN      128
#define DE      32
#define HID     128
#define DOUT    64
#define NMT     (EE / 16)
#define SLOWNB  768
#define HBLK    128
#define CHUNK   (EE / HBLK)   // 5000
#define FBLK    512           // fast edge kernel: 512 blocks x 256 thr (4 waves)
#define NWAVES  (FBLK * 4)    // 2048

// ---- workspace float-element offsets ----
#define ACCF  0        // [64][128] per-graph sum of a
#define CNTF  8192     // [64] edge count per graph (fp32)
#define S1F   8256     // [128] global sum(a)
#define S2F   8384     // [128] global sum(a^2)
#define GXF   8512     // [64][128] per-graph node sums
#define O1F   16704    // [64][128] mlp2 hidden
#define FLGF  24896    // int flags
#define BAT8  24898    // 10240 u8
#define W1F_  27458    // 160*128 fp32
#define B1F_  47938
#define G1F_  48066
#define BE1F_ 48194
#define W2F_  48322
#define B2F_  64706
#define W3F_  64834
#define B3F_  97602
#define G3F_  97730
#define BE3F_ 97858
#define W4F_  97986
#define B4F_  106178
#define YBF   106244   // bf16 y[10000][128] (2.56MB)
#define H32F  746244   // int [128][64] block histograms
#define BSTF  754436   // int [128][64] scatter bases
#define GENDI 762628   // int [64] bucket end (edge units)
#define NTI   762692   // int [1] total tiles
#define T2G   762696   // u8 [40960] tile -> graph
#define SRTE  772936   // int [641024] sorted edge ids
#define WSEND 1413960  // floats (5.66 MB)

typedef __bf16 bf16x8 __attribute__((ext_vector_type(8)));
typedef float  f32x4  __attribute__((ext_vector_type(4)));

__device__ __forceinline__ float lrelu(float v) { return v > 0.f ? v : 0.01f * v; }

__device__ __forceinline__ bf16x8 cvt8(const float* p) {
  const f32x4 a0 = *(const f32x4*)p, a1 = *(const f32x4*)(p + 4);
  bf16x8 t;
  t[0]=(__bf16)a0[0]; t[1]=(__bf16)a0[1]; t[2]=(__bf16)a0[2]; t[3]=(__bf16)a0[3];
  t[4]=(__bf16)a1[0]; t[5]=(__bf16)a1[1]; t[6]=(__bf16)a1[2]; t[7]=(__bf16)a1[3];
  return t;
}

// ---- K0: dtype sniff + zero accumulator head ----
__global__ __launch_bounds__(256) void k_sniff(const unsigned* __restrict__ xw,
                                               const unsigned* __restrict__ ew,
                                               float* __restrict__ ws) {
  const int tid = threadIdx.x;
  for (int i = tid; i < 8512; i += 256) ws[i] = 0.f;
  if (tid < 64) {
    const unsigned w = xw[tid];
    const unsigned ex = (w >> 7) & 0xFFu;
    int cb = (ex >= 100u && ex <= 140u) ? 1 : 0;
    int ci = (ew[2 * tid + 1] == 0u) ? 1 : 0;
#pragma unroll
    for (int s = 1; s < 64; s <<= 1) { cb += __shfl_xor(cb, s); ci += __shfl_xor(ci, s); }
    if (tid == 0) { int* f = (int*)(ws + FLGF); f[0] = (cb >= 48); f[1] = (ci >= 60); }
  }
}

__device__ __forceinline__ void cpyw(float* dst, const void* src, int n, int isb,
                                     int gtid, int gs) {
  if (isb) { const __bf16* s = (const __bf16*)src;
    for (int i = gtid; i < n; i += gs) dst[i] = (float)s[i];
  } else { const float* s = (const float*)src;
    for (int i = gtid; i < n; i += gs) dst[i] = s[i]; }
}

// ---- K1: weights->fp32, bat8 table (+optional histogram for fallback) ----
__global__ __launch_bounds__(256) void k_norm(
    const void* __restrict__ eidx, const void* __restrict__ batch,
    const void* W1, const void* b1, const void* g1, const void* be1,
    const void* W2, const void* b2, const void* W3, const void* b3,
    const void* g3, const void* be3, const void* W4, const void* b4,
    float* __restrict__ ws, const int dohist) {
  const int gtid = blockIdx.x * 256 + threadIdx.x;
  const int gs = gridDim.x * 256;
  const int* f = (const int*)(ws + FLGF);
  const int isb = f[0], isi = f[1];
  cpyw(ws + W1F_, W1, 160 * HID, isb, gtid, gs);
  cpyw(ws + B1F_, b1, HID, isb, gtid, gs);
  cpyw(ws + G1F_, g1, HID, isb, gtid, gs);
  cpyw(ws + BE1F_, be1, HID, isb, gtid, gs);
  cpyw(ws + W2F_, W2, HID * HID, isb, gtid, gs);
  cpyw(ws + B2F_, b2, HID, isb, gtid, gs);
  cpyw(ws + W3F_, W3, 256 * HID, isb, gtid, gs);
  cpyw(ws + B3F_, b3, HID, isb, gtid, gs);
  cpyw(ws + G3F_, g3, HID, isb, gtid, gs);
  cpyw(ws + BE3F_, be3, HID, isb, gtid, gs);
  cpyw(ws + W4F_, W4, HID * DOUT, isb, gtid, gs);
  cpyw(ws + B4F_, b4, DOUT, isb, gtid, gs);
  const int* bs = (const int*)batch;
  unsigned char* b8 = (unsigned char*)(ws + BAT8);
  for (int i = gtid; i < NNODES_; i += gs)
    b8[i] = (unsigned char)((isi ? bs[2 * i] : bs[i]) & 63);
  if (dohist) {
    __shared__ int h[NG];
    if (threadIdx.x < NG) h[threadIdx.x] = 0;
    __syncthreads();
    const int* es = (const int*)eidx;
    for (int e = gtid; e < EE; e += gs) {
      int cl = isi ? es[2 * (EE + e)] : es[EE + e];
      cl = min(max(cl, 0), NNODES_ - 1);
      atomicAdd(&h[(isi ? bs[2 * cl] : bs[cl]) & 63], 1);
    }
    __syncthreads();
    if (threadIdx.x < NG && h[threadIdx.x])
      unsafeAtomicAdd(&ws[CNTF + threadIdx.x], (float)h[threadIdx.x]);
  }
}

// ---- K2h: per-block histogram over edge chunk ----
__global__ __launch_bounds__(256) void k_hist(const void* __restrict__ eidx,
                                              float* __restrict__ ws) {
  __shared__ int h[NG];
  const int tid = threadIdx.x, b = blockIdx.x;
  if (tid < NG) h[tid] = 0;
  __syncthreads();
  const int isi = ((const int*)(ws + FLGF))[1];
  const int* ei32 = (const int*)eidx;
  const unsigned char* bat8 = (const unsigned char*)(ws + BAT8);
  for (int e = b * CHUNK + tid; e < (b + 1) * CHUNK; e += 256) {
    int cl = isi ? ei32[2 * (EE + e)] : ei32[EE + e];
    cl = min(max(cl, 0), NNODES_ - 1);
    atomicAdd(&h[bat8[cl]], 1);
  }
  __syncthreads();
  if (tid < NG) ((int*)(ws + H32F))[b * NG + tid] = h[tid];
}

// ---- K2s: scan -> bucket bases, tile2g, cnt, dummy fill ----
__global__ void k_scan(float* __restrict__ ws) {
  const int g = threadIdx.x;        // 64 threads = 1 wave
  const int* H = (const int*)(ws + H32F);
  int* BS = (int*)(ws + BSTF);
  int cnt = 0;
  for (int b = 0; b < HBLK; ++b) { BS[b * NG + g] = cnt; cnt += H[b * NG + g]; }
  const int pc = (cnt + 15) & ~15;
  int inc = pc;
#pragma unroll
  for (int s = 1; s < 64; s <<= 1) { int u = __shfl_up(inc, s); if (g >= s) inc += u; }
  const int base = inc - pc;
  for (int b = 0; b < HBLK; ++b) BS[b * NG + g] += base;
  ((int*)(ws + GENDI))[g] = base + cnt;
  ws[CNTF + g] = (float)cnt;
  const int tot = __shfl(inc, 63);
  if (g == 0) ((int*)(ws + NTI))[0] = tot >> 4;
  unsigned char* t2 = (unsigned char*)(ws + T2G);
  for (int i = base >> 4; i < (base + pc) >> 4; ++i) t2[i] = (unsigned char)g;
  int* srte = (int*)(ws + SRTE);
  for (int i = cnt; i < pc; ++i) srte[base + i] = 0;
}

// ---- K2c: scatter edge ids to sorted order ----
__global__ __launch_bounds__(256) void k_scat(const void* __restrict__ eidx,
                                              float* __restrict__ ws) {
  __shared__ int cur[NG];
  const int tid = threadIdx.x, b = blockIdx.x;
  if (tid < NG) cur[tid] = ((const int*)(ws + BSTF))[b * NG + tid];
  __syncthreads();
  const int isi = ((const int*)(ws + FLGF))[1];
  const int* ei32 = (const int*)eidx;
  const unsigned char* bat8 = (const unsigned char*)(ws + BAT8);
  int* srte = (int*)(ws + SRTE);
  for (int e = b * CHUNK + tid; e < (b + 1) * CHUNK; e += 256) {
    int cl = isi ? ei32[2 * (EE + e)] : ei32[EE + e];
    cl = min(max(cl, 0), NNODES_ - 1);
    const int pos = atomicAdd(&cur[bat8[cl]], 1);
    srte[pos] = e;
  }
}

// ---- K3: per-graph node-feature sums (batch sorted) ----
__global__ __launch_bounds__(256) void k_gx(
    const void* __restrict__ x, const void* __restrict__ batch, float* __restrict__ ws) {
  const int b = blockIdx.x, tid = threadIdx.x;
  const int isb = ((const int*)(ws + FLGF))[0];
  const int isi = ((const int*)(ws + FLGF))[1];
  const int* bt = (const int*)batch;
#define BATV(i) ((isi ? bt[2 * (i)] : bt[(i)]) & 63)
  int lo = 0, hi = NNODES_;
  while (lo < hi) { int m = (lo + hi) >> 1; if (BATV(m) < b) lo = m + 1; else hi = m; }
  const int r0 = lo;
  hi = NNODES_;
  while (lo < hi) { int m = (lo + hi) >> 1; if (BATV(m) < b + 1) lo = m + 1; else hi = m; }
  const int r1 = lo;
#undef BATV
  const int c = tid & 127, half = tid >> 7;
  float acc = 0.f;
  if (isb) { const __bf16* xs = (const __bf16*)x;
    for (int r = r0 + half; r < r1; r += 2) acc += (float)xs[r * DN + c];
  } else { const float* xs = (const float*)x;
    for (int r = r0 + half; r < r1; r += 2) acc += xs[r * DN + c]; }
  __shared__ float red[256];
  red[tid] = acc;
  __syncthreads();
  if (tid < 128) ws[GXF + b * DN + tid] = red[tid] + red[tid + 128];
}

// ---- K4a: y = x @ W1x + b1 (bf16 out) ----
__global__ __launch_bounds__(256) void k_y(float* __restrict__ ws, const void* __restrict__ x) {
  __shared__ __align__(16) __bf16 w1x[128 * 128];
  const int tid = threadIdx.x;
  const int isb = ((const int*)(ws + FLGF))[0];
  for (int i = tid; i < 128 * 128; i += 256) {
    const int k = i >> 7, n = i & 127;
    w1x[n * 128 + k] = (__bf16)ws[W1F_ + k * HID + n];
  }
  __syncthreads();
  const int lane = tid & 63, wid = tid >> 6, ml = lane & 15, kg = lane >> 4;
  __bf16* ybf = (__bf16*)(ws + YBF);
  for (int t = blockIdx.x * 4 + wid; t < 625; t += 160 * 4) {
    const int n0 = t * 16;
    const int row = n0 + ml;
    bf16x8 af[4];
    if (isb) {
      const __bf16* xp = (const __bf16*)x + row * DN + kg * 8;
#pragma unroll
      for (int ks = 0; ks < 4; ++ks) af[ks] = *(const bf16x8*)(xp + ks * 32);
    } else {
      const float* xp = (const float*)x + row * DN + kg * 8;
#pragma unroll
      for (int ks = 0; ks < 4; ++ks) af[ks] = cvt8(xp + ks * 32);
    }
    f32x4 acc[8] = {{0,0,0,0},{0,0,0,0},{0,0,0,0},{0,0,0,0},
                    {0,0,0,0},{0,0,0,0},{0,0,0,0},{0,0,0,0}};
#pragma unroll
    for (int ks = 0; ks < 4; ++ks) {
#pragma unroll
      for (int nt = 0; nt < 8; ++nt) {
        const bf16x8 bfr = *(const bf16x8*)(w1x + (nt * 16 + ml) * 128 + ks * 32 + kg * 8);
        acc[nt] = __builtin_amdgcn_mfma_f32_16x16x32_bf16(af[ks], bfr, acc[nt], 0, 0, 0);
      }
    }
#pragma unroll
    for (int nt = 0; nt < 8; ++nt) {
      const int c = nt * 16 + ml;
      const float bias = ws[B1F_ + c];
#pragma unroll
      for (int q = 0; q < 4; ++q)
        ybf[(n0 + kg * 4 + q) * HID + c] = (__bf16)(acc[nt][q] + bias);
    }
  }
}

// ---- K4b: sorted edge loop — register accumulation, no LDS in hot loop ----
__global__ __launch_bounds__(256, 4) void k_edgef2(float* __restrict__ ws,
                                                   const void* __restrict__ ea,
                                                   const void* __restrict__ eidx) {
  __shared__ __align__(16) __bf16 w1e[128 * 32];   // 8KB [n][k]
  const int tid = threadIdx.x;
  const int* flg = (const int*)(ws + FLGF);
  const int isb = flg[0], isi = flg[1];
  for (int i = tid; i < 32 * 128; i += 256) {
    const int k = i >> 7, n = i & 127;
    w1e[n * 32 + k] = (__bf16)ws[W1F_ + (128 + k) * HID + n];
  }
  __syncthreads();
  const int lane = tid & 63, wid = tid >> 6, ml = lane & 15, kg = lane >> 4;
  bf16x8 bfe[8];
#pragma unroll
  for (int nt = 0; nt < 8; ++nt)
    bfe[nt] = *(const bf16x8*)(w1e + (nt * 16 + ml) * 32 + kg * 8);
  bf16x8 idf;
#pragma unroll
  for (int j = 0; j < 8; ++j) idf[j] = (kg * 8 + j == ml) ? (__bf16)1.0f : (__bf16)0.0f;

  const int* ei32 = (const int*)eidx;
  const int* srte = (const int*)(ws + SRTE);
  const unsigned char* t2g = (const unsigned char*)(ws + T2G);
  const int* gend = (const int*)(ws + GENDI);
  const __bf16* ybf = (const __bf16*)(ws + YBF);
  const int NT = ((const int*)(ws + NTI))[0];
  const int tpw = (NT + NWAVES - 1) / NWAVES;
  const int wgid = blockIdx.x * 4 + wid;
  const int t0 = wgid * tpw;
  const int t1 = min(t0 + tpw, NT);

  float gsum[8] = {0,0,0,0,0,0,0,0};
  float s1[8] = {0,0,0,0,0,0,0,0}, s2[8] = {0,0,0,0,0,0,0,0};
  int cur_g = (t0 < t1) ? (int)t2g[t0] : -1;

  for (int t = t0; t < t1; ++t) {
    const int g = (int)t2g[t];
    if (g != cur_g) {   // wave-uniform, rare
#pragma unroll
      for (int nt = 0; nt < 8; ++nt) {
        float v = gsum[nt];
        v += __shfl_xor(v, 16); v += __shfl_xor(v, 32);
        if (kg == 0) unsafeAtomicAdd(&ws[ACCF + cur_g * HID + nt * 16 + ml], v);
        gsum[nt] = 0.f;
      }
      cur_g = g;
    }
    const int ge = gend[g];
    const int eidm = srte[t * 16 + ml];
    int r = isi ? ei32[2 * eidm] : ei32[eidm];
    r = min(max(r, 0), NNODES_ - 1);
    bf16x8 ae;
    if (isb) ae = *(const bf16x8*)((const __bf16*)ea + (size_t)eidm * DE + kg * 8);
    else     ae = cvt8((const float*)ea + (size_t)eidm * DE + kg * 8);
    f32x4 acc[8] = {{0,0,0,0},{0,0,0,0},{0,0,0,0},{0,0,0,0},
                    {0,0,0,0},{0,0,0,0},{0,0,0,0},{0,0,0,0}};
#pragma unroll
    for (int nt = 0; nt < 8; ++nt)
      acc[nt] = __builtin_amdgcn_mfma_f32_16x16x32_bf16(ae, bfe[nt], acc[nt], 0, 0, 0);
    const __bf16* yb = ybf + (size_t)r * HID + (kg & 1) * 8;
#pragma unroll
    for (int nt = 0; nt < 8; ++nt) {
      const bf16x8 ay = *(const bf16x8*)(yb + nt * 16);
      acc[nt] = __builtin_amdgcn_mfma_f32_16x16x32_bf16(ay, idf, acc[nt], 0, 0, 0);
    }
    const int eb = t * 16 + kg * 4;
#pragma unroll
    for (int nt = 0; nt < 8; ++nt) {
#pragma unroll
      for (int q = 0; q < 4; ++q) {
        const float v = (eb + q < ge) ? lrelu(acc[nt][q]) : 0.f;
        gsum[nt] += v;
        s1[nt] += v;
        s2[nt] += v * v;
      }
    }
  }
  if (cur_g >= 0) {
#pragma unroll
    for (int nt = 0; nt < 8; ++nt) {
      float v = gsum[nt];
      v += __shfl_xor(v, 16); v += __shfl_xor(v, 32);
      if (kg == 0) unsafeAtomicAdd(&ws[ACCF + cur_g * HID + nt * 16 + ml], v);
    }
  }
#pragma unroll
  for (int nt = 0; nt < 8; ++nt) {
    float v1 = s1[nt], v2 = s2[nt];
    v1 += __shfl_xor(v1, 16); v1 += __shfl_xor(v1, 32);
    v2 += __shfl_xor(v2, 16); v2 += __shfl_xor(v2, 32);
    if (kg == 0) {
      unsafeAtomicAdd(&ws[S1F + nt * 16 + ml], v1);
      unsafeAtomicAdd(&ws[S2F + nt * 16 + ml], v2);
    }
  }
}

// ---- K4s: slow fallback (proven) ----
__global__ __launch_bounds__(256) void k_edges_slow(
    float* __restrict__ ws, const void* __restrict__ x, const void* __restrict__ ea,
    const void* __restrict__ eidx) {
  __shared__ __align__(16) char smem[40960];
  float* lacc = (float*)smem;
  __bf16* w1t = (__bf16*)smem;
  const int tid = threadIdx.x;
  const int* flg = (const int*)(ws + FLGF);
  const int isb = flg[0], isi = flg[1];
  for (int i = tid; i < 160 * HID; i += 256) {
    const int k = i >> 7, n = i & 127;
    w1t[n * 160 + k] = (__bf16)ws[W1F_ + i];
  }
  __syncthreads();
  const int lane = tid & 63, wid = tid >> 6;
  const int ml = lane & 15, kg = lane >> 4;
  const int ch0 = (wid & 1) * 64;
  const int pair = blockIdx.x * 2 + (wid >> 1);
  bf16x8 bfr[5][4];
  float b1v[4];
#pragma unroll
  for (int nt = 0; nt < 4; ++nt) {
    const int n = ch0 + nt * 16 + ml;
    b1v[nt] = ws[B1F_ + n];
#pragma unroll
    for (int ks = 0; ks < 5; ++ks)
      bfr[ks][nt] = *(const bf16x8*)(w1t + n * 160 + ks * 32 + kg * 8);
  }
  __syncthreads();
  for (int i = tid; i < NG * 132; i += 256) lacc[i] = 0.f;
  __syncthreads();
  float s1a[4] = {0,0,0,0}, s2a[4] = {0,0,0,0};
  const int* ei32 = (const int*)eidx;
  const unsigned char* bat8 = (const unsigned char*)(ws + BAT8);
  for (int mt = pair; mt < NMT; mt += 2 * SLOWNB) {
    const int em = mt * 16 + ml;
    int r  = isi ? ei32[2 * em] : ei32[em];
    int cl = isi ? ei32[2 * (EE + em)] : ei32[EE + em];
    r  = min(max(r, 0), NNODES_ - 1);
    cl = min(max(cl, 0), NNODES_ - 1);
    const int gg = bat8[cl];
    f32x4 acc[4] = {{0,0,0,0},{0,0,0,0},{0,0,0,0},{0,0,0,0}};
#pragma unroll
    for (int ks = 0; ks < 4; ++ks) {
      bf16x8 afr;
      if (isb) afr = *(const bf16x8*)((const __bf16*)x + r * DN + ks * 32 + kg * 8);
      else     afr = cvt8((const float*)x + r * DN + ks * 32 + kg * 8);
#pragma unroll
      for (int nt = 0; nt < 4; ++nt)
        acc[nt] = __builtin_amdgcn_mfma_f32_16x16x32_bf16(afr, bfr[ks][nt], acc[nt], 0, 0, 0);
    }
    {
      bf16x8 t;
      if (isb) t = *(const bf16x8*)((const __bf16*)ea + em * DE + kg * 8);
      else     t = cvt8((const float*)ea + em * DE + kg * 8);
#pragma unroll
      for (int nt = 0; nt < 4; ++nt)
        acc[nt] = __builtin_amdgcn_mfma_f32_16x16x32_bf16(t, bfr[4][nt], acc[nt], 0, 0, 0);
    }
    int gR[4];
#pragma unroll
    for (int q = 0; q < 4; ++q) gR[q] = __shfl(gg, kg * 4 + q);
#pragma unroll
    for (int nt = 0; nt < 4; ++nt) {
      const int c = ch0 + nt * 16 + ml;
#pragma unroll
      for (int q = 0; q < 4; ++q) {
        const float v = lrelu(acc[nt][q] + b1v[nt]);
        s1a[nt] += v;
        s2a[nt] += v * v;
        atomicAdd(&lacc[gR[q] * 132 + c], v);
      }
    }
  }
#pragma unroll
  for (int nt = 0; nt < 4; ++nt) {
    float v1 = s1a[nt], v2 = s2a[nt];
    v1 += __shfl_xor(v1, 16); v1 += __shfl_xor(v1, 32);
    v2 += __shfl_xor(v2, 16); v2 += __shfl_xor(v2, 32);
    if (lane < 16) {
      unsafeAtomicAdd(&ws[S1F + ch0 + nt * 16 + lane], v1);
      unsafeAtomicAdd(&ws[S2F + ch0 + nt * 16 + lane], v2);
    }
  }
  __syncthreads();
  for (int i = tid; i < NG * HID; i += 256)
    unsafeAtomicAdd(&ws[ACCF + i], lacc[(i >> 7) * 132 + (i & 127)]);
}

// ---- K5: BN1-affine + go GEMM + MLP2 layer1 ----
__global__ __launch_bounds__(128) void k_graph(float* __restrict__ ws) {
  const int b = blockIdx.x, c = threadIdx.x;
  const float invE = 1.f / (float)EE;
  const float mu  = ws[S1F + c] * invE;
  const float var = ws[S2F + c] * invE - mu * mu;
  const float s   = ws[G1F_ + c] * rsqrtf(var + 1e-5f);
  const float t   = ws[BE1F_ + c] - mu * s;
  const float cb  = ws[CNTF + b];
  __shared__ float zsh[HID];
  __shared__ float gv[DN + HID];
  zsh[c] = s * ws[ACCF + b * HID + c] + cb * t;
  gv[c]  = ws[GXF + b * DN + c];
  __syncthreads();
  float a = cb * ws[B2F_ + c];
  for (int k = 0; k < HID; ++k) a += zsh[k] * ws[W2F_ + k * HID + c];
  gv[DN + c] = a;
  __syncthreads();
  float h = ws[B3F_ + c];
  for (int j = 0; j < DN + HID; ++j) h += gv[j] * ws[W3F_ + j * HID + c];
  ws[O1F + b * HID + c] = lrelu(h);
}

// ---- K6: BN over graphs + final Lin(128,64) ----
__global__ __launch_bounds__(64) void k_out(const float* __restrict__ ws,
                                            void* __restrict__ out) {
  const int b = blockIdx.x, o = threadIdx.x;
  const int isb = ((const int*)(ws + FLGF))[0];
  __shared__ float zrow[HID];
  for (int cc = o; cc < HID; cc += 64) {
    float sm = 0.f, sq = 0.f;
    for (int r = 0; r < NG; ++r) { const float v = ws[O1F + r * HID + cc]; sm += v; sq += v * v; }
    const float mu  = sm * (1.f / NG);
    const float var = sq * (1.f / NG) - mu * mu;
    const float sc  = ws[G3F_ + cc] * rsqrtf(var + 1e-5f);
    zrow[cc] = ws[O1F + b * HID + cc] * sc + (ws[BE3F_ + cc] - mu * sc);
  }
  __syncthreads();
  float a = ws[B4F_ + o];
  for (int k = 0; k < HID; ++k) a += zrow[k] * ws[W4F_ + k * DOUT + o];
  if (isb) ((__bf16*)out)[b * DOUT + o] = (__bf16)a;
  else     ((float*)out)[b * DOUT + o] = a;
}

extern "C" void kernel_launch(void* const* d_in, const int* in_sizes, int n_in,
                              void* d_out, int out_size, void* d_ws, size_t ws_size,
                              hipStream_t stream) {
  float* ws = (float*)d_ws;
  const int fast = (ws_size >= (size_t)WSEND * 4) ? 1 : 0;   // 5.66 MB
  hipLaunchKernelGGL(k_sniff, dim3(1), dim3(256), 0, stream,
                     (const unsigned*)d_in[0], (const unsigned*)d_in[1], ws);
  hipLaunchKernelGGL(k_norm, dim3(256), dim3(256), 0, stream,
                     d_in[1], d_in[4],
                     d_in[5], d_in[6], d_in[7], d_in[8],
                     d_in[9], d_in[10], d_in[11], d_in[12],
                     d_in[13], d_in[14], d_in[15], d_in[16], ws, fast ? 0 : 1);
  hipLaunchKernelGGL(k_gx, dim3(NG), dim3(256), 0, stream, d_in[0], d_in[4], ws);
  if (fast) {
    hipLaunchKernelGGL(k_hist, dim3(HBLK), dim3(256), 0, stream, d_in[1], ws);
    hipLaunchKernelGGL(k_scan, dim3(1), dim3(64), 0, stream, ws);
    hipLaunchKernelGGL(k_scat, dim3(HBLK), dim3(256), 0, stream, d_in[1], ws);
    hipLaunchKernelGGL(k_y, dim3(160), dim3(256), 0, stream, ws, d_in[0]);
    hipLaunchKernelGGL(k_edgef2, dim3(FBLK), dim3(256), 0, stream, ws, d_in[2], d_in[1]);
  } else {
    hipLaunchKernelGGL(k_edges_slow, dim3(SLOWNB), dim3(256), 0, stream,
                       ws, d_in[0], d_in[2], d_in[1]);
  }
  hipLaunchKernelGGL(k_graph, dim3(NG), dim3(128), 0, stream, ws);
  hipLaunchKernelGGL(k_out, dim3(NG), dim3(64), 0, stream, ws, d_out);
}